// Round 4
// baseline (300.850 us; speedup 1.0000x reference)
//
#include <hip/hip_runtime.h>

#define DD 128   // feature dim D
#define HH 128   // hidden dim H
#define KK 32    // neighbors per node
#define TM 64    // gemm rows per block (4 waves x 16)

typedef _Float16 half8 __attribute__((ext_vector_type(8)));
typedef float    f32x4 __attribute__((ext_vector_type(4)));
typedef ushort   us8   __attribute__((ext_vector_type(8)));

__device__ __forceinline__ float h2f(ushort s) {
    return (float)__builtin_bit_cast(_Float16, s);
}
__device__ __forceinline__ ushort f2h(float f) {
    return __builtin_bit_cast(ushort, (_Float16)f);
}

// ---------------------------------------------------------------------------
// Kernel 0: Wt[h][k] = f16(W[k][h])  — one-time 64KB transpose+convert.
// ---------------------------------------------------------------------------
__global__ __launch_bounds__(128) void prep_wt(const float* __restrict__ W,
                                               ushort* __restrict__ Wt) {
    const int k = blockIdx.x;      // 0..127
    const int h = threadIdx.x;     // 0..127
    Wt[h * DD + k] = f2h(W[(size_t)k * HH + h]);
}

// ---------------------------------------------------------------------------
// Kernel 1: y_f16 = f16(x @ W) via MFMA 16x16x32_f16 — LDS-free.
// A-fragment: lane-local 32B f32 read of x, converted in-register.
// B-fragment: 16B read of Wt (32KB, L1/L2-resident, broadcast over blocks).
// Block: 4 waves x 16 rows = 64 rows; each wave covers all 128 cols (8 tiles).
// ---------------------------------------------------------------------------
__global__ __launch_bounds__(256) void gemm_mfma(const float* __restrict__ x,
                                                 const ushort* __restrict__ Wt,
                                                 ushort* __restrict__ yb, int N) {
    const int t    = threadIdx.x;
    const int wid  = t >> 6;
    const int lane = t & 63;
    const int am   = lane & 15;    // A row / B col within 16-tile
    const int grp  = lane >> 4;    // k-group 0..3
    const int row0 = blockIdx.x * TM;

    const int arow = row0 + wid * 16 + am;
    const int rclamp = (arow < N) ? arow : (N - 1);
    const float4* x4 = (const float4*)x + (size_t)rclamp * (DD / 4);

    f32x4 acc[8];
#pragma unroll
    for (int i = 0; i < 8; ++i) acc[i] = (f32x4){0.f, 0.f, 0.f, 0.f};

#pragma unroll
    for (int ks = 0; ks < 4; ++ks) {
        const int k0 = ks * 32 + grp * 8;
        float4 xa = x4[k0 / 4];
        float4 xb = x4[k0 / 4 + 1];
        half8 a;
        a[0] = (_Float16)xa.x; a[1] = (_Float16)xa.y;
        a[2] = (_Float16)xa.z; a[3] = (_Float16)xa.w;
        a[4] = (_Float16)xb.x; a[5] = (_Float16)xb.y;
        a[6] = (_Float16)xb.z; a[7] = (_Float16)xb.w;
#pragma unroll
        for (int ct = 0; ct < 8; ++ct) {
            half8 bf = *(const half8*)&Wt[(ct * 16 + am) * DD + k0];
            acc[ct] = __builtin_amdgcn_mfma_f32_16x16x32_f16(a, bf, acc[ct], 0, 0, 0);
        }
    }

    // C/D layout: col = lane&15, row = (lane>>4)*4 + j
#pragma unroll
    for (int ct = 0; ct < 8; ++ct) {
#pragma unroll
        for (int j = 0; j < 4; ++j) {
            int gr = row0 + wid * 16 + grp * 4 + j;
            if (gr < N)
                yb[(size_t)gr * HH + ct * 16 + am] = f2h(acc[ct][j]);
        }
    }
}

// ---------------------------------------------------------------------------
// Kernel 2: out[n,h] = (1/K)*sum_k max(y[j], c) - c,  c = y[n] - b  (f16 y)
// 16 nodes per 256-thread block; 16 lanes x ushort8 (16B) per row.
// Gathers issued in register batches of 8; VGPR cap 85 (6 waves/SIMD) so the
// scheduler keeps many misses in flight.
// ---------------------------------------------------------------------------
__global__ __launch_bounds__(256, 6) void edge_mean(const ushort* __restrict__ yb,
                                                    const float* __restrict__ b,
                                                    const int* __restrict__ eidx,
                                                    float* __restrict__ out, int N) {
    __shared__ int sidx[16][KK];
    const int node_l = threadIdx.x >> 4;    // 0..15
    const int l16    = threadIdx.x & 15;
    const int n      = blockIdx.x * 16 + node_l;
    const int tot    = N * KK;

    {   // stage 512 indices, coalesced
        int base = blockIdx.x * 16 * KK;
        int i0 = base + threadIdx.x, i1 = base + 256 + threadIdx.x;
        ((int*)sidx)[threadIdx.x]       = (i0 < tot) ? eidx[i0] : 0;
        ((int*)sidx)[256 + threadIdx.x] = (i1 < tot) ? eidx[i1] : 0;
    }

    const us8* y8 = (const us8*)yb;
    float c[8];
    {
        float4 b0 = ((const float4*)b)[l16 * 2];
        float4 b1 = ((const float4*)b)[l16 * 2 + 1];
        us8 cv = (n < N) ? y8[(size_t)n * (HH / 8) + l16] : (us8){0,0,0,0,0,0,0,0};
        c[0] = h2f(cv[0]) - b0.x; c[1] = h2f(cv[1]) - b0.y;
        c[2] = h2f(cv[2]) - b0.z; c[3] = h2f(cv[3]) - b0.w;
        c[4] = h2f(cv[4]) - b1.x; c[5] = h2f(cv[5]) - b1.y;
        c[6] = h2f(cv[6]) - b1.z; c[7] = h2f(cv[7]) - b1.w;
    }
    __syncthreads();
    if (n >= N) return;

    float acc[8];
#pragma unroll
    for (int i = 0; i < 8; ++i) acc[i] = 0.f;

#pragma unroll
    for (int kb = 0; kb < KK / 8; ++kb) {
        us8 v[8];
#pragma unroll
        for (int u = 0; u < 8; ++u) {
            int j = sidx[node_l][kb * 8 + u];
            v[u] = y8[(size_t)j * (HH / 8) + l16];
        }
#pragma unroll
        for (int u = 0; u < 8; ++u) {
#pragma unroll
            for (int i = 0; i < 8; ++i)
                acc[i] += fmaxf(h2f(v[u][i]), c[i]);
        }
    }

    float4 o0, o1;
    o0.x = acc[0] * (1.0f / KK) - c[0]; o0.y = acc[1] * (1.0f / KK) - c[1];
    o0.z = acc[2] * (1.0f / KK) - c[2]; o0.w = acc[3] * (1.0f / KK) - c[3];
    o1.x = acc[4] * (1.0f / KK) - c[4]; o1.y = acc[5] * (1.0f / KK) - c[5];
    o1.z = acc[6] * (1.0f / KK) - c[6]; o1.w = acc[7] * (1.0f / KK) - c[7];
    ((float4*)out)[(size_t)n * (HH / 4) + l16 * 2]     = o0;
    ((float4*)out)[(size_t)n * (HH / 4) + l16 * 2 + 1] = o1;
}

// ---------------------------------------------------------------------------
// Fallback (only if ws_size too small): fused direct compute, correct but slow.
// ---------------------------------------------------------------------------
__global__ __launch_bounds__(128) void direct_conv(const float* __restrict__ x,
                                                   const float* __restrict__ W,
                                                   const float* __restrict__ b,
                                                   const int* __restrict__ eidx,
                                                   float* __restrict__ out, int N) {
    __shared__ float sxi[DD];
    __shared__ float sdiff[DD];
    __shared__ int   sidx[KK];
    const int t = threadIdx.x;
    const int n = blockIdx.x;
    if (n >= N) return;

    sxi[t] = x[(size_t)n * DD + t];
    if (t < KK) sidx[t] = eidx[(size_t)n * KK + t];
    __syncthreads();

    float acc = 0.f;
    const float bb = b[t];
    for (int k = 0; k < KK; ++k) {
        int j = sidx[k];
        sdiff[t] = x[(size_t)j * DD + t] - sxi[t];
        __syncthreads();
        float dot = bb;
#pragma unroll 8
        for (int d = 0; d < DD; ++d)
            dot = fmaf(sdiff[d], W[(size_t)d * HH + t], dot);
        acc += fmaxf(dot, 0.f);
        __syncthreads();
    }
    out[(size_t)n * HH + t] = acc * (1.0f / KK);
}

extern "C" void kernel_launch(void* const* d_in, const int* in_sizes, int n_in,
                              void* d_out, int out_size, void* d_ws, size_t ws_size,
                              hipStream_t stream) {
    const float* x    = (const float*)d_in[0];
    const float* W    = (const float*)d_in[1];
    const float* b    = (const float*)d_in[2];
    const int*   eidx = (const int*)d_in[3];
    float*       out  = (float*)d_out;
    const int N = in_sizes[0] / DD;

    const size_t wt_bytes = (size_t)DD * HH * sizeof(ushort);   // 32 KB
    const size_t need = wt_bytes + (size_t)N * HH * sizeof(ushort);
    if (ws_size >= need) {
        ushort* Wt = (ushort*)d_ws;
        ushort* yb = (ushort*)((char*)d_ws + wt_bytes);
        prep_wt<<<DD, 128, 0, stream>>>(W, Wt);
        gemm_mfma<<<(N + TM - 1) / TM, 256, 0, stream>>>(x, Wt, yb, N);
        edge_mean<<<(N + 15) / 16, 256, 0, stream>>>(yb, b, eidx, out, N);
    } else {
        direct_conv<<<N, 128, 0, stream>>>(x, W, b, eidx, out, N);
    }
}

// Round 5
// 79.699 us; speedup vs baseline: 3.7748x; 3.7748x over previous
//
#include <hip/hip_runtime.h>

#define DD 128   // feature dim D
#define HH 128   // hidden dim H
#define KK 32    // neighbors per node
#define TM 64    // gemm rows per block (4 waves x 16)

typedef _Float16 half8 __attribute__((ext_vector_type(8)));
typedef float    f32x4 __attribute__((ext_vector_type(4)));
typedef ushort   us8   __attribute__((ext_vector_type(8)));

__device__ __forceinline__ float h2f(ushort s) {
    return (float)__builtin_bit_cast(_Float16, s);
}
__device__ __forceinline__ ushort f2h(float f) {
    return __builtin_bit_cast(ushort, (_Float16)f);
}

// ---------------------------------------------------------------------------
// Kernel 0: Wt[h][k] = f16(W[k][h])  — one-time 32KB transpose+convert.
// ---------------------------------------------------------------------------
__global__ __launch_bounds__(128) void prep_wt(const float* __restrict__ W,
                                               ushort* __restrict__ Wt) {
    const int k = blockIdx.x;      // 0..127
    const int h = threadIdx.x;     // 0..127
    Wt[h * DD + k] = f2h(W[(size_t)k * HH + h]);
}

// ---------------------------------------------------------------------------
// Kernel 1: y_f16 = f16(x @ W) via MFMA 16x16x32_f16 — LDS-free.
// A-fragment: lane-local 32B f32 read of x, converted in-register.
// B-fragment: 16B read of Wt (32KB, L1/L2-resident, broadcast over blocks).
// ---------------------------------------------------------------------------
__global__ __launch_bounds__(256) void gemm_mfma(const float* __restrict__ x,
                                                 const ushort* __restrict__ Wt,
                                                 ushort* __restrict__ yb, int N) {
    const int t    = threadIdx.x;
    const int wid  = t >> 6;
    const int lane = t & 63;
    const int am   = lane & 15;    // A row / B col within 16-tile
    const int grp  = lane >> 4;    // k-group 0..3
    const int row0 = blockIdx.x * TM;

    const int arow = row0 + wid * 16 + am;
    const int rclamp = (arow < N) ? arow : (N - 1);
    const float4* x4 = (const float4*)x + (size_t)rclamp * (DD / 4);

    f32x4 acc[8];
#pragma unroll
    for (int i = 0; i < 8; ++i) acc[i] = (f32x4){0.f, 0.f, 0.f, 0.f};

#pragma unroll
    for (int ks = 0; ks < 4; ++ks) {
        const int k0 = ks * 32 + grp * 8;
        float4 xa = x4[k0 / 4];
        float4 xb = x4[k0 / 4 + 1];
        half8 a;
        a[0] = (_Float16)xa.x; a[1] = (_Float16)xa.y;
        a[2] = (_Float16)xa.z; a[3] = (_Float16)xa.w;
        a[4] = (_Float16)xb.x; a[5] = (_Float16)xb.y;
        a[6] = (_Float16)xb.z; a[7] = (_Float16)xb.w;
#pragma unroll
        for (int ct = 0; ct < 8; ++ct) {
            half8 bf = *(const half8*)&Wt[(ct * 16 + am) * DD + k0];
            acc[ct] = __builtin_amdgcn_mfma_f32_16x16x32_f16(a, bf, acc[ct], 0, 0, 0);
        }
    }

    // C/D layout: col = lane&15, row = (lane>>4)*4 + j
#pragma unroll
    for (int ct = 0; ct < 8; ++ct) {
#pragma unroll
        for (int j = 0; j < 4; ++j) {
            int gr = row0 + wid * 16 + grp * 4 + j;
            if (gr < N)
                yb[(size_t)gr * HH + ct * 16 + am] = f2h(acc[ct][j]);
        }
    }
}

// ---------------------------------------------------------------------------
// Kernel 2: out[n,h] = (1/K)*sum_k max(y[j], c) - c,  c = y[n] - b  (f16 y)
// 16 nodes per 256-thread block; 16 lanes x ushort8 (16B) per row.
// Gathers in strict batches of 4 (32 VGPRs in flight, no spill); default
// launch bounds so the allocator is unconstrained.
// ---------------------------------------------------------------------------
__global__ __launch_bounds__(256) void edge_mean(const ushort* __restrict__ yb,
                                                 const float* __restrict__ b,
                                                 const int* __restrict__ eidx,
                                                 float* __restrict__ out, int N) {
    __shared__ int sidx[16][KK];
    const int node_l = threadIdx.x >> 4;    // 0..15
    const int l16    = threadIdx.x & 15;
    const int n      = blockIdx.x * 16 + node_l;
    const int tot    = N * KK;

    {   // stage 512 indices, coalesced
        int base = blockIdx.x * 16 * KK;
        int i0 = base + threadIdx.x, i1 = base + 256 + threadIdx.x;
        ((int*)sidx)[threadIdx.x]       = (i0 < tot) ? eidx[i0] : 0;
        ((int*)sidx)[256 + threadIdx.x] = (i1 < tot) ? eidx[i1] : 0;
    }

    const us8* y8 = (const us8*)yb;
    float c[8];
    {
        float4 b0 = ((const float4*)b)[l16 * 2];
        float4 b1 = ((const float4*)b)[l16 * 2 + 1];
        us8 cv = (n < N) ? y8[(size_t)n * (HH / 8) + l16] : (us8){0,0,0,0,0,0,0,0};
        c[0] = h2f(cv[0]) - b0.x; c[1] = h2f(cv[1]) - b0.y;
        c[2] = h2f(cv[2]) - b0.z; c[3] = h2f(cv[3]) - b0.w;
        c[4] = h2f(cv[4]) - b1.x; c[5] = h2f(cv[5]) - b1.y;
        c[6] = h2f(cv[6]) - b1.z; c[7] = h2f(cv[7]) - b1.w;
    }
    __syncthreads();
    if (n >= N) return;

    float acc[8];
#pragma unroll
    for (int i = 0; i < 8; ++i) acc[i] = 0.f;

#pragma unroll 1
    for (int kb = 0; kb < KK / 4; ++kb) {   // strict batches of 4 gathers
        us8 v0 = y8[(size_t)sidx[node_l][kb * 4 + 0] * (HH / 8) + l16];
        us8 v1 = y8[(size_t)sidx[node_l][kb * 4 + 1] * (HH / 8) + l16];
        us8 v2 = y8[(size_t)sidx[node_l][kb * 4 + 2] * (HH / 8) + l16];
        us8 v3 = y8[(size_t)sidx[node_l][kb * 4 + 3] * (HH / 8) + l16];
#pragma unroll
        for (int i = 0; i < 8; ++i) {
            acc[i] += fmaxf(h2f(v0[i]), c[i]);
            acc[i] += fmaxf(h2f(v1[i]), c[i]);
            acc[i] += fmaxf(h2f(v2[i]), c[i]);
            acc[i] += fmaxf(h2f(v3[i]), c[i]);
        }
    }

    float4 o0, o1;
    o0.x = acc[0] * (1.0f / KK) - c[0]; o0.y = acc[1] * (1.0f / KK) - c[1];
    o0.z = acc[2] * (1.0f / KK) - c[2]; o0.w = acc[3] * (1.0f / KK) - c[3];
    o1.x = acc[4] * (1.0f / KK) - c[4]; o1.y = acc[5] * (1.0f / KK) - c[5];
    o1.z = acc[6] * (1.0f / KK) - c[6]; o1.w = acc[7] * (1.0f / KK) - c[7];
    ((float4*)out)[(size_t)n * (HH / 4) + l16 * 2]     = o0;
    ((float4*)out)[(size_t)n * (HH / 4) + l16 * 2 + 1] = o1;
}

// ---------------------------------------------------------------------------
// Fallback (only if ws_size too small): fused direct compute, correct but slow.
// ---------------------------------------------------------------------------
__global__ __launch_bounds__(128) void direct_conv(const float* __restrict__ x,
                                                   const float* __restrict__ W,
                                                   const float* __restrict__ b,
                                                   const int* __restrict__ eidx,
                                                   float* __restrict__ out, int N) {
    __shared__ float sxi[DD];
    __shared__ float sdiff[DD];
    __shared__ int   sidx[KK];
    const int t = threadIdx.x;
    const int n = blockIdx.x;
    if (n >= N) return;

    sxi[t] = x[(size_t)n * DD + t];
    if (t < KK) sidx[t] = eidx[(size_t)n * KK + t];
    __syncthreads();

    float acc = 0.f;
    const float bb = b[t];
    for (int k = 0; k < KK; ++k) {
        int j = sidx[k];
        sdiff[t] = x[(size_t)j * DD + t] - sxi[t];
        __syncthreads();
        float dot = bb;
#pragma unroll 8
        for (int d = 0; d < DD; ++d)
            dot = fmaf(sdiff[d], W[(size_t)d * HH + t], dot);
        acc += fmaxf(dot, 0.f);
        __syncthreads();
    }
    out[(size_t)n * HH + t] = acc * (1.0f / KK);
}

extern "C" void kernel_launch(void* const* d_in, const int* in_sizes, int n_in,
                              void* d_out, int out_size, void* d_ws, size_t ws_size,
                              hipStream_t stream) {
    const float* x    = (const float*)d_in[0];
    const float* W    = (const float*)d_in[1];
    const float* b    = (const float*)d_in[2];
    const int*   eidx = (const int*)d_in[3];
    float*       out  = (float*)d_out;
    const int N = in_sizes[0] / DD;

    const size_t wt_bytes = (size_t)DD * HH * sizeof(ushort);   // 32 KB
    const size_t need = wt_bytes + (size_t)N * HH * sizeof(ushort);
    if (ws_size >= need) {
        ushort* Wt = (ushort*)d_ws;
        ushort* yb = (ushort*)((char*)d_ws + wt_bytes);
        prep_wt<<<DD, 128, 0, stream>>>(W, Wt);
        gemm_mfma<<<(N + TM - 1) / TM, 256, 0, stream>>>(x, Wt, yb, N);
        edge_mean<<<(N + 15) / 16, 256, 0, stream>>>(yb, b, eidx, out, N);
    } else {
        direct_conv<<<N, 128, 0, stream>>>(x, W, b, eidx, out, N);
    }
}

// Round 6
// 79.439 us; speedup vs baseline: 3.7872x; 1.0033x over previous
//
#include <hip/hip_runtime.h>

#define DD 128   // feature dim D
#define HH 128   // hidden dim H
#define KK 32    // neighbors per node
#define TMG 32   // gemm rows per block (2 row-groups x 16, col-split 2 waves)

typedef _Float16 half8 __attribute__((ext_vector_type(8)));
typedef float    f32x4 __attribute__((ext_vector_type(4)));
typedef ushort   us8   __attribute__((ext_vector_type(8)));

__device__ __forceinline__ float h2f(ushort s) {
    return (float)__builtin_bit_cast(_Float16, s);
}
__device__ __forceinline__ ushort f2h(float f) {
    return __builtin_bit_cast(ushort, (_Float16)f);
}

// ---------------------------------------------------------------------------
// Kernel 0: Wt[h][k] = f16(W[k][h]) — 16 blocks, LDS-staged transpose.
// ---------------------------------------------------------------------------
__global__ __launch_bounds__(256) void prep_wt(const float* __restrict__ W,
                                               ushort* __restrict__ Wt) {
    __shared__ float sw[8 * HH];     // 4 KB
    const int t  = threadIdx.x;
    const int k0 = blockIdx.x * 8;   // 8 k-rows per block
    ((float4*)sw)[t] = ((const float4*)(W + (size_t)k0 * HH))[t];
    __syncthreads();
    if (t < HH) {
        us8 o;
#pragma unroll
        for (int dk = 0; dk < 8; ++dk) o[dk] = f2h(sw[dk * HH + t]);
        *(us8*)(Wt + (size_t)t * DD + k0) = o;
    }
}

// ---------------------------------------------------------------------------
// Kernel 1: y_f16 = f16(x @ W) via MFMA 16x16x32_f16 — LDS-free main loop.
// Operands SWAPPED: A = Wt rows (h), B = x rows (n) -> D col = x-row,
// D rows = h -> each lane packs 4 consecutive h as ushort4.
// Epilogue: packed 8B writes to padded LDS tile, then coalesced 16B stores.
// Block: 4 waves; (wid>>1) = row-group of 16, (wid&1) = col-half of 64.
// ---------------------------------------------------------------------------
__global__ __launch_bounds__(256) void gemm_mfma(const float* __restrict__ x,
                                                 const ushort* __restrict__ Wt,
                                                 ushort* __restrict__ yb, int N) {
    __shared__ ushort sy[TMG][HH + 8];   // 32 x 136 us = 8704 B (16B-aligned rows)
    const int t    = threadIdx.x;
    const int wid  = t >> 6;
    const int lane = t & 63;
    const int am   = lane & 15;
    const int grp  = lane >> 4;
    const int rgrp = wid >> 1;           // 0/1
    const int cgrp = wid & 1;            // 0/1
    const int row0 = blockIdx.x * TMG;

    const int arow = row0 + rgrp * 16 + am;
    const int rclamp = (arow < N) ? arow : (N - 1);
    const float4* x4 = (const float4*)x + (size_t)rclamp * (DD / 4);

    f32x4 acc[4];
#pragma unroll
    for (int i = 0; i < 4; ++i) acc[i] = (f32x4){0.f, 0.f, 0.f, 0.f};

#pragma unroll
    for (int ks = 0; ks < 4; ++ks) {
        const int k0 = ks * 32 + grp * 8;
        float4 xa = x4[k0 / 4];
        float4 xb = x4[k0 / 4 + 1];
        half8 bfrag;                     // x is the B operand now
        bfrag[0] = (_Float16)xa.x; bfrag[1] = (_Float16)xa.y;
        bfrag[2] = (_Float16)xa.z; bfrag[3] = (_Float16)xa.w;
        bfrag[4] = (_Float16)xb.x; bfrag[5] = (_Float16)xb.y;
        bfrag[6] = (_Float16)xb.z; bfrag[7] = (_Float16)xb.w;
#pragma unroll
        for (int ct = 0; ct < 4; ++ct) {
            const int hrow = cgrp * 64 + ct * 16 + am;     // Wt row = A tile row
            half8 afrag = *(const half8*)&Wt[hrow * DD + k0];
            acc[ct] = __builtin_amdgcn_mfma_f32_16x16x32_f16(afrag, bfrag, acc[ct], 0, 0, 0);
        }
    }

    // lane holds y[x_row][h0..h0+3] per ct;  h0 = cgrp*64 + ct*16 + grp*4
    const int lrow = rgrp * 16 + am;
#pragma unroll
    for (int ct = 0; ct < 4; ++ct) {
        const int h0 = cgrp * 64 + ct * 16 + grp * 4;
        *reinterpret_cast<ushort4*>(&sy[lrow][h0]) =
            make_ushort4(f2h(acc[ct][0]), f2h(acc[ct][1]),
                         f2h(acc[ct][2]), f2h(acc[ct][3]));
    }
    __syncthreads();

    // coalesced writeout: 32 rows x 128 us = 512 x 16B chunks, 2 per thread
#pragma unroll
    for (int i = 0; i < 2; ++i) {
        int c   = t + i * 256;           // 0..511
        int r   = c >> 4;                // 16 chunks per row
        int col = (c & 15) * 8;          // ushort offset
        int gr  = row0 + r;
        if (gr < N)
            *(us8*)(yb + (size_t)gr * HH + col) = *(const us8*)&sy[r][col];
    }
}

// ---------------------------------------------------------------------------
// Kernel 2: out[n,h] = (1/K)*sum_k max(y[j], c) - c,  c = y[n] - b  (f16 y)
// 16 nodes per 256-thread block; 16 lanes x ushort8 (16B) per row.
// Strict batches of 4 gathers (no spill). Unchanged from round 5.
// ---------------------------------------------------------------------------
__global__ __launch_bounds__(256) void edge_mean(const ushort* __restrict__ yb,
                                                 const float* __restrict__ b,
                                                 const int* __restrict__ eidx,
                                                 float* __restrict__ out, int N) {
    __shared__ int sidx[16][KK];
    const int node_l = threadIdx.x >> 4;    // 0..15
    const int l16    = threadIdx.x & 15;
    const int n      = blockIdx.x * 16 + node_l;
    const int tot    = N * KK;

    {   // stage 512 indices, coalesced
        int base = blockIdx.x * 16 * KK;
        int i0 = base + threadIdx.x, i1 = base + 256 + threadIdx.x;
        ((int*)sidx)[threadIdx.x]       = (i0 < tot) ? eidx[i0] : 0;
        ((int*)sidx)[256 + threadIdx.x] = (i1 < tot) ? eidx[i1] : 0;
    }

    const us8* y8 = (const us8*)yb;
    float c[8];
    {
        float4 b0 = ((const float4*)b)[l16 * 2];
        float4 b1 = ((const float4*)b)[l16 * 2 + 1];
        us8 cv = (n < N) ? y8[(size_t)n * (HH / 8) + l16] : (us8){0,0,0,0,0,0,0,0};
        c[0] = h2f(cv[0]) - b0.x; c[1] = h2f(cv[1]) - b0.y;
        c[2] = h2f(cv[2]) - b0.z; c[3] = h2f(cv[3]) - b0.w;
        c[4] = h2f(cv[4]) - b1.x; c[5] = h2f(cv[5]) - b1.y;
        c[6] = h2f(cv[6]) - b1.z; c[7] = h2f(cv[7]) - b1.w;
    }
    __syncthreads();
    if (n >= N) return;

    float acc[8];
#pragma unroll
    for (int i = 0; i < 8; ++i) acc[i] = 0.f;

#pragma unroll 1
    for (int kb = 0; kb < KK / 4; ++kb) {   // strict batches of 4 gathers
        us8 v0 = y8[(size_t)sidx[node_l][kb * 4 + 0] * (HH / 8) + l16];
        us8 v1 = y8[(size_t)sidx[node_l][kb * 4 + 1] * (HH / 8) + l16];
        us8 v2 = y8[(size_t)sidx[node_l][kb * 4 + 2] * (HH / 8) + l16];
        us8 v3 = y8[(size_t)sidx[node_l][kb * 4 + 3] * (HH / 8) + l16];
#pragma unroll
        for (int i = 0; i < 8; ++i) {
            acc[i] += fmaxf(h2f(v0[i]), c[i]);
            acc[i] += fmaxf(h2f(v1[i]), c[i]);
            acc[i] += fmaxf(h2f(v2[i]), c[i]);
            acc[i] += fmaxf(h2f(v3[i]), c[i]);
        }
    }

    float4 o0, o1;
    o0.x = acc[0] * (1.0f / KK) - c[0]; o0.y = acc[1] * (1.0f / KK) - c[1];
    o0.z = acc[2] * (1.0f / KK) - c[2]; o0.w = acc[3] * (1.0f / KK) - c[3];
    o1.x = acc[4] * (1.0f / KK) - c[4]; o1.y = acc[5] * (1.0f / KK) - c[5];
    o1.z = acc[6] * (1.0f / KK) - c[6]; o1.w = acc[7] * (1.0f / KK) - c[7];
    ((float4*)out)[(size_t)n * (HH / 4) + l16 * 2]     = o0;
    ((float4*)out)[(size_t)n * (HH / 4) + l16 * 2 + 1] = o1;
}

// ---------------------------------------------------------------------------
// Fallback (only if ws_size too small): fused direct compute, correct but slow.
// ---------------------------------------------------------------------------
__global__ __launch_bounds__(128) void direct_conv(const float* __restrict__ x,
                                                   const float* __restrict__ W,
                                                   const float* __restrict__ b,
                                                   const int* __restrict__ eidx,
                                                   float* __restrict__ out, int N) {
    __shared__ float sxi[DD];
    __shared__ float sdiff[DD];
    __shared__ int   sidx[KK];
    const int t = threadIdx.x;
    const int n = blockIdx.x;
    if (n >= N) return;

    sxi[t] = x[(size_t)n * DD + t];
    if (t < KK) sidx[t] = eidx[(size_t)n * KK + t];
    __syncthreads();

    float acc = 0.f;
    const float bb = b[t];
    for (int k = 0; k < KK; ++k) {
        int j = sidx[k];
        sdiff[t] = x[(size_t)j * DD + t] - sxi[t];
        __syncthreads();
        float dot = bb;
#pragma unroll 8
        for (int d = 0; d < DD; ++d)
            dot = fmaf(sdiff[d], W[(size_t)d * HH + t], dot);
        acc += fmaxf(dot, 0.f);
        __syncthreads();
    }
    out[(size_t)n * HH + t] = acc * (1.0f / KK);
}

extern "C" void kernel_launch(void* const* d_in, const int* in_sizes, int n_in,
                              void* d_out, int out_size, void* d_ws, size_t ws_size,
                              hipStream_t stream) {
    const float* x    = (const float*)d_in[0];
    const float* W    = (const float*)d_in[1];
    const float* b    = (const float*)d_in[2];
    const int*   eidx = (const int*)d_in[3];
    float*       out  = (float*)d_out;
    const int N = in_sizes[0] / DD;

    const size_t wt_bytes = (size_t)DD * HH * sizeof(ushort);   // 32 KB
    const size_t need = wt_bytes + (size_t)N * HH * sizeof(ushort);
    if (ws_size >= need) {
        ushort* Wt = (ushort*)d_ws;
        ushort* yb = (ushort*)((char*)d_ws + wt_bytes);
        prep_wt<<<DD / 8, 256, 0, stream>>>(W, Wt);
        gemm_mfma<<<(N + TMG - 1) / TMG, 256, 0, stream>>>(x, Wt, yb, N);
        edge_mean<<<(N + 15) / 16, 256, 0, stream>>>(yb, b, eidx, out, N);
    } else {
        direct_conv<<<N, 128, 0, stream>>>(x, W, b, eidx, out, N);
    }
}